// Round 9
// baseline (90.242 us; speedup 1.0000x reference)
//
#include <hip/hip_runtime.h>
#include <hip/hip_bf16.h>

// B=32, S=1024, D=768, HD=64 single-head attention, scores scaled 1/D.
// Inputs fp32, output fp32 [B,S,HD].
// Pipeline: (0) W -> bf16 fragment-major Wtf, (1) QKV proj: NO LDS — A
// fragments loaded directly from global x (L1/L2 serve the 4x intra-block
// reuse), cvt_pk to bf16 in registers, B lane-linear from L2-resident Wtf;
// zero barriers, TLP-based latency hiding. Q pre-scaled by 1/768*log2e,
// V stored transposed [B][H][S]. (2) flash attention, 32x32 swapped-QK^T,
// max-free exp2 softmax, 4-way key-split + sum-merge.

constexpr int NB = 32;
constexpr int NS = 1024;
constexpr int ND = 768;
constexpr int NH = 64;
constexpr float SC2 = (1.0f / 768.0f) * 1.4426950408889634f;

typedef __attribute__((ext_vector_type(8))) short bf16x8;
typedef __attribute__((ext_vector_type(4))) float f32x4;
typedef __attribute__((ext_vector_type(16))) float f32x16;
typedef __attribute__((ext_vector_type(4))) unsigned int u32x4;

__device__ __forceinline__ unsigned short f2bf(float f) {
    unsigned int u = __float_as_uint(f);
    u += 0x7FFFu + ((u >> 16) & 1u);   // RNE
    return (unsigned short)(u >> 16);
}

__device__ __forceinline__ unsigned int pkbf(float lo, float hi) {
    __hip_bfloat162 h = __float22bfloat162_rn(float2{lo, hi});
    return *reinterpret_cast<unsigned int*>(&h);
}

__device__ __forceinline__ void pl32swap(unsigned int a, unsigned int b,
                                         unsigned int& x, unsigned int& y) {
    auto r = __builtin_amdgcn_permlane32_swap((int)a, (int)b, false, false);
    x = (unsigned int)r[0];
    y = (unsigned int)r[1];
}

__device__ __forceinline__ float xswap_add(float v) {
    unsigned int a, b;
    pl32swap(__float_as_uint(v), __float_as_uint(v), a, b);
    return __uint_as_float(a) + __uint_as_float(b);
}

// ---------------- Kernel 0: W -> fragment-major Wtf --------------------------
// Position p = f*512 + lane*8 + e holds W_n[k] with f = nt*24+ks,
// n = nt*16 + (lane&15), k = ks*32 + (lane>>4)*8 + e.
__global__ void wtrans_kernel(const float* __restrict__ Wq, const float* __restrict__ Wk,
                              const float* __restrict__ Wv, short* __restrict__ Wtf) {
    int idx = blockIdx.x * 256 + threadIdx.x;      // 147456 = 576*256
    int f = idx >> 9, q = idx & 511;
    int lane = q >> 3, e = q & 7;
    int ln = lane & 15, g = lane >> 4;
    int nt = f / 24, ks = f - nt * 24;
    int n = nt * 16 + ln;
    int k = ks * 32 + g * 8 + e;
    const float* W = (n < 64) ? Wq : ((n < 128) ? Wk : Wv);
    Wtf[idx] = (short)f2bf(W[(size_t)k * NH + (n & 63)]);
}

// ---------------- Kernel 1: QKV projection (no LDS, no barriers) -------------
// Tile: 32 M x 192 N x full-K. 4 waves, wave wi owns cols [wi*48, wi*48+48).
// A fragments direct from global (rows m0+mf*16+ln, k = ks*32+g*8..+8);
// sibling waves' repeated A reads are L1/L2 hits.
__global__ __launch_bounds__(256, 4) void qkv_kernel(
    const float* __restrict__ x, const short* __restrict__ Wtf,
    const float* __restrict__ bq, const float* __restrict__ bk, const float* __restrict__ bv,
    short* __restrict__ Qw, short* __restrict__ Kw, short* __restrict__ Vwt)
{
    const int t = threadIdx.x;
    const int wi = t >> 6, lane = t & 63, ln = lane & 15, g = lane >> 4;
    const int m0 = blockIdx.x * 32;

    const float* ar0 = x + (size_t)(m0 + ln) * ND + g * 8;   // mf = 0 rows
    const float* ar1 = ar0 + (size_t)16 * ND;                 // mf = 1 rows
    const short* bbase = Wtf + (size_t)(wi * 3) * 24 * 512 + lane * 8;

    f32x4 acc[2][3];
    #pragma unroll
    for (int i = 0; i < 2; i++)
        #pragma unroll
        for (int j = 0; j < 3; j++) acc[i][j] = f32x4{0.f, 0.f, 0.f, 0.f};

    #pragma unroll 2
    for (int ks = 0; ks < 24; ks++) {
        // A: 8 fp32 per row-set (two float4), offsets fold into imm
        float4 a00 = *(const float4*)(ar0 + ks * 32);
        float4 a01 = *(const float4*)(ar0 + ks * 32 + 4);
        float4 a10 = *(const float4*)(ar1 + ks * 32);
        float4 a11 = *(const float4*)(ar1 + ks * 32 + 4);
        // B: three lane-linear 1 KB fragments from L2
        bf16x8 b0 = *(const bf16x8*)(bbase + (0 * 24 + ks) * 512);
        bf16x8 b1 = *(const bf16x8*)(bbase + (1 * 24 + ks) * 512);
        bf16x8 b2 = *(const bf16x8*)(bbase + (2 * 24 + ks) * 512);

        u32x4 v0{pkbf(a00.x, a00.y), pkbf(a00.z, a00.w),
                 pkbf(a01.x, a01.y), pkbf(a01.z, a01.w)};
        u32x4 v1{pkbf(a10.x, a10.y), pkbf(a10.z, a10.w),
                 pkbf(a11.x, a11.y), pkbf(a11.z, a11.w)};
        bf16x8 af0 = *reinterpret_cast<bf16x8*>(&v0);
        bf16x8 af1 = *reinterpret_cast<bf16x8*>(&v1);

        acc[0][0] = __builtin_amdgcn_mfma_f32_16x16x32_bf16(af0, b0, acc[0][0], 0, 0, 0);
        acc[0][1] = __builtin_amdgcn_mfma_f32_16x16x32_bf16(af0, b1, acc[0][1], 0, 0, 0);
        acc[0][2] = __builtin_amdgcn_mfma_f32_16x16x32_bf16(af0, b2, acc[0][2], 0, 0, 0);
        acc[1][0] = __builtin_amdgcn_mfma_f32_16x16x32_bf16(af1, b0, acc[1][0], 0, 0, 0);
        acc[1][1] = __builtin_amdgcn_mfma_f32_16x16x32_bf16(af1, b1, acc[1][1], 0, 0, 0);
        acc[1][2] = __builtin_amdgcn_mfma_f32_16x16x32_bf16(af1, b2, acc[1][2], 0, 0, 0);
    }

    // ---- epilogue: +bias (Q also * SC2), cast bf16, store
    #pragma unroll
    for (int nf = 0; nf < 3; nf++) {
        int n = wi * 48 + nf * 16 + ln;
        int mat = n >> 6, col = n & 63;
        const float* bp = (mat == 0) ? bq : ((mat == 1) ? bk : bv);
        float bias = bp[col];
        #pragma unroll
        for (int mf = 0; mf < 2; mf++) {
            int rbase = m0 + mf * 16 + g * 4;
            #pragma unroll
            for (int r = 0; r < 4; r++) {
                float v = acc[mf][nf][r] + bias;
                int row = rbase + r;
                if (mat == 0) {
                    Qw[(size_t)row * NH + col] = (short)f2bf(v * SC2);
                } else if (mat == 1) {
                    Kw[(size_t)row * NH + col] = (short)f2bf(v);
                } else {
                    int bb = row >> 10, ss = row & 1023;
                    Vwt[((size_t)bb * NH + col) * NS + ss] = (short)f2bf(v);
                }
            }
        }
    }
}

// ---------------- Kernel 2: flash attention (32x32 swapped QK^T) -------------
// Grid: (16 q-tiles, 32 batches), 512 threads = 8 waves = 4 key-groups x 2 q-waves.
__global__ __launch_bounds__(512, 4) void attn_kernel(
    const short* __restrict__ Qw, const short* __restrict__ Kw,
    const short* __restrict__ Vwt, float* __restrict__ out)
{
    __shared__ __align__(16) short sm[4][2][64][72];  // [gk][0]=K, [gk][1]=V

    const int t = threadIdx.x;
    const int w = t >> 6;
    const int lane = t & 63, l31 = lane & 31, h32 = lane >> 5;
    const int gk = w >> 1, wq = w & 1;
    const int b = blockIdx.y, qt = blockIdx.x;

    short (*Ks)[72] = sm[gk][0];
    short (*Vs)[72] = sm[gk][1];

    const short* qbase = Qw + ((size_t)(b * NS + qt * 64 + wq * 32 + l31)) * NH + h32 * 8;
    bf16x8 qf[4];
    #pragma unroll
    for (int ks = 0; ks < 4; ks++) qf[ks] = *(const bf16x8*)(qbase + ks * 16);

    f32x16 oacc[2];
    #pragma unroll
    for (int i = 0; i < 16; i++) { oacc[0][i] = 0.f; oacc[1][i] = 0.f; }
    float l_part = 0.f;

    const int tg = t & 127;
    const int srow = tg >> 1, scb = (tg & 1) * 32;
    const int key00 = gk * 256;
    const short* ksrc = Kw + ((size_t)(b * NS + key00 + srow)) * NH + scb;
    const short* vsrc = Vwt + ((size_t)(b * NH + srow)) * NS + key00 + scb;

    bf16x8 kpre[4], vpre[4];
    #pragma unroll
    for (int i = 0; i < 4; i++) {
        kpre[i] = *(const bf16x8*)(ksrc + i * 8);
        vpre[i] = *(const bf16x8*)(vsrc + i * 8);
    }
    #pragma unroll
    for (int i = 0; i < 4; i++) {
        *(bf16x8*)&Ks[srow][scb + i * 8] = kpre[i];
        *(bf16x8*)&Vs[srow][scb + i * 8] = vpre[i];
    }
    __syncthreads();

    constexpr int NT = 4;
    for (int kt = 0; kt < NT; kt++) {
        if (kt < NT - 1) {
            const short* kp = ksrc + (size_t)(kt + 1) * 64 * NH;
            const short* vp = vsrc + (kt + 1) * 64;
            #pragma unroll
            for (int i = 0; i < 4; i++) {
                kpre[i] = *(const bf16x8*)(kp + i * 8);
                vpre[i] = *(const bf16x8*)(vp + i * 8);
            }
        }

        float sl = 0.f;
        u32x4 pw[4];

        // ---- keys [0,32): S^T = K*Q^T, exp2, pack -> pw[0..1]
        {
            f32x16 st;
            #pragma unroll
            for (int i = 0; i < 16; i++) st[i] = 0.f;
            __builtin_amdgcn_s_setprio(1);
            #pragma unroll
            for (int ks = 0; ks < 4; ks++) {
                bf16x8 a0 = *(const bf16x8*)&Ks[l31][ks * 16 + h32 * 8];
                st = __builtin_amdgcn_mfma_f32_32x32x16_bf16(a0, qf[ks], st, 0, 0, 0);
            }
            __builtin_amdgcn_s_setprio(0);
            #pragma unroll
            for (int i = 0; i < 16; i++) { st[i] = exp2f(st[i]); sl += st[i]; }
            unsigned int c[8];
            #pragma unroll
            for (int i = 0; i < 8; i++) c[i] = pkbf(st[2 * i], st[2 * i + 1]);
            unsigned int w0, w1, w2, w3;
            pl32swap(c[0], c[2], w0, w2); pl32swap(c[1], c[3], w1, w3);
            pw[0] = u32x4{w0, w1, w2, w3};
            pl32swap(c[4], c[6], w0, w2); pl32swap(c[5], c[7], w1, w3);
            pw[1] = u32x4{w0, w1, w2, w3};
        }
        // ---- keys [32,64)
        {
            f32x16 st;
            #pragma unroll
            for (int i = 0; i < 16; i++) st[i] = 0.f;
            __builtin_amdgcn_s_setprio(1);
            #pragma unroll
            for (int ks = 0; ks < 4; ks++) {
                bf16x8 a1 = *(const bf16x8*)&Ks[32 + l31][ks * 16 + h32 * 8];
                st = __builtin_amdgcn_mfma_f32_32x32x16_bf16(a1, qf[ks], st, 0, 0, 0);
            }
            __builtin_amdgcn_s_setprio(0);
            #pragma unroll
            for (int i = 0; i < 16; i++) { st[i] = exp2f(st[i]); sl += st[i]; }
            unsigned int c[8];
            #pragma unroll
            for (int i = 0; i < 8; i++) c[i] = pkbf(st[2 * i], st[2 * i + 1]);
            unsigned int w0, w1, w2, w3;
            pl32swap(c[0], c[2], w0, w2); pl32swap(c[1], c[3], w1, w3);
            pw[2] = u32x4{w0, w1, w2, w3};
            pl32swap(c[4], c[6], w0, w2); pl32swap(c[5], c[7], w1, w3);
            pw[3] = u32x4{w0, w1, w2, w3};
        }
        l_part += sl;

        // ---- O^T += V^T * P^T
        __builtin_amdgcn_s_setprio(1);
        #pragma unroll
        for (int ks = 0; ks < 4; ks++) {
            bf16x8 pb = *(bf16x8*)&pw[ks];
            #pragma unroll
            for (int ht = 0; ht < 2; ht++) {
                bf16x8 va = *(const bf16x8*)&Vs[ht * 32 + l31][ks * 16 + h32 * 8];
                oacc[ht] = __builtin_amdgcn_mfma_f32_32x32x16_bf16(va, pb, oacc[ht], 0, 0, 0);
            }
        }
        __builtin_amdgcn_s_setprio(0);

        if (kt < NT - 1) {
            __syncthreads();
            #pragma unroll
            for (int i = 0; i < 4; i++) {
                *(bf16x8*)&Ks[srow][scb + i * 8] = kpre[i];
                *(bf16x8*)&Vs[srow][scb + i * 8] = vpre[i];
            }
            __syncthreads();
        }
    }

    // ---- merge groups: pure sums (m=0 shared reference). LDS reused as f32.
    float l_run = xswap_add(l_part);
    __syncthreads();
    float* mg = (float*)&sm[0][0][0][0];
    constexpr int SLOT = 64 * 69;
    constexpr int LBASE = 3 * SLOT;
    const int qloc = wq * 32 + l31;
    if (gk > 0) {
        float* ob = mg + (gk - 1) * SLOT + qloc * 69;
        #pragma unroll
        for (int ht = 0; ht < 2; ht++)
            #pragma unroll
            for (int r = 0; r < 16; r++)
                ob[ht * 32 + (r & 3) + 8 * (r >> 2) + 4 * h32] = oacc[ht][r];
        if (h32 == 0) mg[LBASE + (gk - 1) * 64 + qloc] = l_run;
    }
    __syncthreads();
    if (gk == 0) {
        float l_tot = l_run + mg[LBASE + qloc] + mg[LBASE + 64 + qloc] + mg[LBASE + 128 + qloc];
        float linv = 1.0f / l_tot;
        float* op = out + ((size_t)(b * NS + qt * 64 + qloc)) * NH;
        const float* o1 = mg + qloc * 69;
        #pragma unroll
        for (int ht = 0; ht < 2; ht++)
            #pragma unroll
            for (int r = 0; r < 16; r++) {
                int hv = ht * 32 + (r & 3) + 8 * (r >> 2) + 4 * h32;
                float s = oacc[ht][r] + o1[hv] + o1[SLOT + hv] + o1[2 * SLOT + hv];
                op[hv] = s * linv;
            }
    }
}

// ---------------- launcher ---------------------------------------------------
extern "C" void kernel_launch(void* const* d_in, const int* in_sizes, int n_in,
                              void* d_out, int out_size, void* d_ws, size_t ws_size,
                              hipStream_t stream)
{
    const float* x  = (const float*)d_in[0];
    const float* Wq = (const float*)d_in[1];
    const float* bq = (const float*)d_in[2];
    const float* Wk = (const float*)d_in[3];
    const float* bk = (const float*)d_in[4];
    const float* Wv = (const float*)d_in[5];
    const float* bv = (const float*)d_in[6];
    float* out = (float*)d_out;

    const size_t qkv_elems = (size_t)NB * NS * NH;   // 2,097,152
    short* Qw  = (short*)d_ws;
    short* Kw  = Qw + qkv_elems;
    short* Vwt = Kw + qkv_elems;                     // [B][64][1024]
    short* Wtf = Vwt + qkv_elems;                    // 192*768 bf16, fragment-major

    wtrans_kernel<<<576, 256, 0, stream>>>(Wq, Wk, Wv, Wtf);
    qkv_kernel<<<(NB * NS) / 32, 256, 0, stream>>>(x, Wtf, bq, bk, bv, Qw, Kw, Vwt);
    attn_kernel<<<dim3(NS / 64, NB), 512, 0, stream>>>(Qw, Kw, Vwt, out);
}

// Round 10
// 73.789 us; speedup vs baseline: 1.2230x; 1.2230x over previous
//
#include <hip/hip_runtime.h>
#include <hip/hip_bf16.h>

// B=32, S=1024, D=768, HD=64 single-head attention, scores scaled 1/D.
// Inputs fp32, output fp32 [B,S,HD].
// Pipeline: (0) W -> bf16 fragment-major Wtf, (1) QKV proj: 32-row full-K
// fp32 panel staged via global_load_lds (async DMA, 12 dwordx4/thread, no
// VGPR round-trip), 16B-granule XOR swizzle via pre-swizzled global source
// (LDS dest stays linear), one vmcnt(0)+barrier, then barrier-free K-loop:
// swizzled ds_read_b128 + cvt_pk + lane-linear B from L2-resident Wtf.
// Q pre-scaled by 1/768*log2e, V stored transposed [B][H][S].
// (2) flash attention, 32x32 swapped-QK^T, max-free exp2 softmax,
// 4-way key-split + sum-merge.

constexpr int NB = 32;
constexpr int NS = 1024;
constexpr int ND = 768;
constexpr int NH = 64;
constexpr float SC2 = (1.0f / 768.0f) * 1.4426950408889634f;

typedef __attribute__((ext_vector_type(8))) short bf16x8;
typedef __attribute__((ext_vector_type(4))) float f32x4;
typedef __attribute__((ext_vector_type(16))) float f32x16;
typedef __attribute__((ext_vector_type(4))) unsigned int u32x4;

__device__ __forceinline__ unsigned short f2bf(float f) {
    unsigned int u = __float_as_uint(f);
    u += 0x7FFFu + ((u >> 16) & 1u);   // RNE
    return (unsigned short)(u >> 16);
}

__device__ __forceinline__ unsigned int pkbf(float lo, float hi) {
    __hip_bfloat162 h = __float22bfloat162_rn(float2{lo, hi});
    return *reinterpret_cast<unsigned int*>(&h);
}

__device__ __forceinline__ void pl32swap(unsigned int a, unsigned int b,
                                         unsigned int& x, unsigned int& y) {
    auto r = __builtin_amdgcn_permlane32_swap((int)a, (int)b, false, false);
    x = (unsigned int)r[0];
    y = (unsigned int)r[1];
}

__device__ __forceinline__ float xswap_add(float v) {
    unsigned int a, b;
    pl32swap(__float_as_uint(v), __float_as_uint(v), a, b);
    return __uint_as_float(a) + __uint_as_float(b);
}

// ---------------- Kernel 0: W -> fragment-major Wtf --------------------------
// Position p = f*512 + lane*8 + e holds W_n[k] with f = nt*24+ks,
// n = nt*16 + (lane&15), k = ks*32 + (lane>>4)*8 + e.
__global__ void wtrans_kernel(const float* __restrict__ Wq, const float* __restrict__ Wk,
                              const float* __restrict__ Wv, short* __restrict__ Wtf) {
    int idx = blockIdx.x * 256 + threadIdx.x;      // 147456 = 576*256
    int f = idx >> 9, q = idx & 511;
    int lane = q >> 3, e = q & 7;
    int ln = lane & 15, g = lane >> 4;
    int nt = f / 24, ks = f - nt * 24;
    int n = nt * 16 + ln;
    int k = ks * 32 + g * 8 + e;
    const float* W = (n < 64) ? Wq : ((n < 128) ? Wk : Wv);
    Wtf[idx] = (short)f2bf(W[(size_t)k * NH + (n & 63)]);
}

// ---------------- Kernel 1: QKV projection (global_load_lds staging) ---------
// Tile: 32 M x 192 N x full-K. 512 threads = 8 waves (2 M-groups x 4 N-groups),
// wave (wm,wn) computes rows [wm*16,+16) x cols [wn*48,+48).
// LDS panel: 32 x 768 fp32 (96 KB), swizzled layout: LDS 16B-chunk (row, pc)
// holds global chunk (row, pc ^ (row&7)).
__global__ __launch_bounds__(512, 2) void qkv_kernel(
    const float* __restrict__ x, const short* __restrict__ Wtf,
    const float* __restrict__ bq, const float* __restrict__ bk, const float* __restrict__ bv,
    short* __restrict__ Qw, short* __restrict__ Kw, short* __restrict__ Vwt)
{
    __shared__ __align__(16) float As[32 * 768];   // 96 KB

    const int t = threadIdx.x;
    const int w = t >> 6, lane = t & 63, ln = lane & 15, g = lane >> 4;
    const int wm = w >> 2, wn = w & 3;
    const int m0 = blockIdx.x * 32;
    const char* xblk = (const char*)(x + (size_t)m0 * ND);

    // ---- stage: 12 async 16B DMA issues per thread; source pre-swizzled
    #pragma unroll
    for (int i = 0; i < 12; i++) {
        int C = i * 512 + t;                 // 16B-chunk id, 0..6143
        int row = C / 192;                   // 192 chunks per 768-float row
        int rem = C - row * 192;
        int sc = rem ^ (row & 7);            // pre-swizzled source chunk
        const void* gp = (const void*)(xblk + (size_t)row * 3072 + (size_t)sc * 16);
        void* lp = (void*)((char*)As + (size_t)(i * 512 + w * 64) * 16);  // wave-uniform
        __builtin_amdgcn_global_load_lds(
            (const __attribute__((address_space(1))) void*)gp,
            (__attribute__((address_space(3))) void*)lp, 16, 0, 0);
    }

    const int arow = wm * 16 + ln;
    const size_t rowoff = (size_t)arow * 3072;
    const int sw = (arow & 7) << 4;
    const short* bbase = Wtf + (size_t)(wn * 3) * 24 * 512 + lane * 8;

    f32x4 acc[3];
    #pragma unroll
    for (int j = 0; j < 3; j++) acc[j] = f32x4{0.f, 0.f, 0.f, 0.f};

    asm volatile("s_waitcnt vmcnt(0)" ::: "memory");
    __syncthreads();

    // ---- K-loop: no barriers
    #pragma unroll 4
    for (int ks = 0; ks < 24; ks++) {
        int c0 = ks * 128 + g * 32;          // byte offset of this lane's 8 floats
        f32x4 lo = *(const f32x4*)((const char*)As + rowoff + (size_t)(c0 ^ sw));
        f32x4 hi = *(const f32x4*)((const char*)As + rowoff + (size_t)((c0 + 16) ^ sw));
        bf16x8 b0 = *(const bf16x8*)(bbase + (0 * 24 + ks) * 512);
        bf16x8 b1 = *(const bf16x8*)(bbase + (1 * 24 + ks) * 512);
        bf16x8 b2 = *(const bf16x8*)(bbase + (2 * 24 + ks) * 512);
        u32x4 v{pkbf(lo[0], lo[1]), pkbf(lo[2], lo[3]),
                pkbf(hi[0], hi[1]), pkbf(hi[2], hi[3])};
        bf16x8 af = *reinterpret_cast<bf16x8*>(&v);
        acc[0] = __builtin_amdgcn_mfma_f32_16x16x32_bf16(af, b0, acc[0], 0, 0, 0);
        acc[1] = __builtin_amdgcn_mfma_f32_16x16x32_bf16(af, b1, acc[1], 0, 0, 0);
        acc[2] = __builtin_amdgcn_mfma_f32_16x16x32_bf16(af, b2, acc[2], 0, 0, 0);
    }

    // ---- epilogue: +bias (Q also * SC2), cast bf16, store
    #pragma unroll
    for (int nf = 0; nf < 3; nf++) {
        int n = wn * 48 + nf * 16 + ln;
        int mat = n >> 6, col = n & 63;
        const float* bp = (mat == 0) ? bq : ((mat == 1) ? bk : bv);
        float bias = bp[col];
        int rbase = m0 + wm * 16 + g * 4;
        #pragma unroll
        for (int r = 0; r < 4; r++) {
            float v = acc[nf][r] + bias;
            int row = rbase + r;
            if (mat == 0) {
                Qw[(size_t)row * NH + col] = (short)f2bf(v * SC2);
            } else if (mat == 1) {
                Kw[(size_t)row * NH + col] = (short)f2bf(v);
            } else {
                int bb = row >> 10, ss = row & 1023;
                Vwt[((size_t)bb * NH + col) * NS + ss] = (short)f2bf(v);
            }
        }
    }
}

// ---------------- Kernel 2: flash attention (32x32 swapped QK^T) -------------
// Grid: (16 q-tiles, 32 batches), 512 threads = 8 waves = 4 key-groups x 2 q-waves.
__global__ __launch_bounds__(512, 4) void attn_kernel(
    const short* __restrict__ Qw, const short* __restrict__ Kw,
    const short* __restrict__ Vwt, float* __restrict__ out)
{
    __shared__ __align__(16) short sm[4][2][64][72];  // [gk][0]=K, [gk][1]=V

    const int t = threadIdx.x;
    const int w = t >> 6;
    const int lane = t & 63, l31 = lane & 31, h32 = lane >> 5;
    const int gk = w >> 1, wq = w & 1;
    const int b = blockIdx.y, qt = blockIdx.x;

    short (*Ks)[72] = sm[gk][0];
    short (*Vs)[72] = sm[gk][1];

    const short* qbase = Qw + ((size_t)(b * NS + qt * 64 + wq * 32 + l31)) * NH + h32 * 8;
    bf16x8 qf[4];
    #pragma unroll
    for (int ks = 0; ks < 4; ks++) qf[ks] = *(const bf16x8*)(qbase + ks * 16);

    f32x16 oacc[2];
    #pragma unroll
    for (int i = 0; i < 16; i++) { oacc[0][i] = 0.f; oacc[1][i] = 0.f; }
    float l_part = 0.f;

    const int tg = t & 127;
    const int srow = tg >> 1, scb = (tg & 1) * 32;
    const int key00 = gk * 256;
    const short* ksrc = Kw + ((size_t)(b * NS + key00 + srow)) * NH + scb;
    const short* vsrc = Vwt + ((size_t)(b * NH + srow)) * NS + key00 + scb;

    bf16x8 kpre[4], vpre[4];
    #pragma unroll
    for (int i = 0; i < 4; i++) {
        kpre[i] = *(const bf16x8*)(ksrc + i * 8);
        vpre[i] = *(const bf16x8*)(vsrc + i * 8);
    }
    #pragma unroll
    for (int i = 0; i < 4; i++) {
        *(bf16x8*)&Ks[srow][scb + i * 8] = kpre[i];
        *(bf16x8*)&Vs[srow][scb + i * 8] = vpre[i];
    }
    __syncthreads();

    constexpr int NT = 4;
    for (int kt = 0; kt < NT; kt++) {
        if (kt < NT - 1) {
            const short* kp = ksrc + (size_t)(kt + 1) * 64 * NH;
            const short* vp = vsrc + (kt + 1) * 64;
            #pragma unroll
            for (int i = 0; i < 4; i++) {
                kpre[i] = *(const bf16x8*)(kp + i * 8);
                vpre[i] = *(const bf16x8*)(vp + i * 8);
            }
        }

        float sl = 0.f;
        u32x4 pw[4];

        // ---- keys [0,32): S^T = K*Q^T, exp2, pack -> pw[0..1]
        {
            f32x16 st;
            #pragma unroll
            for (int i = 0; i < 16; i++) st[i] = 0.f;
            __builtin_amdgcn_s_setprio(1);
            #pragma unroll
            for (int ks = 0; ks < 4; ks++) {
                bf16x8 a0 = *(const bf16x8*)&Ks[l31][ks * 16 + h32 * 8];
                st = __builtin_amdgcn_mfma_f32_32x32x16_bf16(a0, qf[ks], st, 0, 0, 0);
            }
            __builtin_amdgcn_s_setprio(0);
            #pragma unroll
            for (int i = 0; i < 16; i++) { st[i] = exp2f(st[i]); sl += st[i]; }
            unsigned int c[8];
            #pragma unroll
            for (int i = 0; i < 8; i++) c[i] = pkbf(st[2 * i], st[2 * i + 1]);
            unsigned int w0, w1, w2, w3;
            pl32swap(c[0], c[2], w0, w2); pl32swap(c[1], c[3], w1, w3);
            pw[0] = u32x4{w0, w1, w2, w3};
            pl32swap(c[4], c[6], w0, w2); pl32swap(c[5], c[7], w1, w3);
            pw[1] = u32x4{w0, w1, w2, w3};
        }
        // ---- keys [32,64)
        {
            f32x16 st;
            #pragma unroll
            for (int i = 0; i < 16; i++) st[i] = 0.f;
            __builtin_amdgcn_s_setprio(1);
            #pragma unroll
            for (int ks = 0; ks < 4; ks++) {
                bf16x8 a1 = *(const bf16x8*)&Ks[32 + l31][ks * 16 + h32 * 8];
                st = __builtin_amdgcn_mfma_f32_32x32x16_bf16(a1, qf[ks], st, 0, 0, 0);
            }
            __builtin_amdgcn_s_setprio(0);
            #pragma unroll
            for (int i = 0; i < 16; i++) { st[i] = exp2f(st[i]); sl += st[i]; }
            unsigned int c[8];
            #pragma unroll
            for (int i = 0; i < 8; i++) c[i] = pkbf(st[2 * i], st[2 * i + 1]);
            unsigned int w0, w1, w2, w3;
            pl32swap(c[0], c[2], w0, w2); pl32swap(c[1], c[3], w1, w3);
            pw[2] = u32x4{w0, w1, w2, w3};
            pl32swap(c[4], c[6], w0, w2); pl32swap(c[5], c[7], w1, w3);
            pw[3] = u32x4{w0, w1, w2, w3};
        }
        l_part += sl;

        // ---- O^T += V^T * P^T
        __builtin_amdgcn_s_setprio(1);
        #pragma unroll
        for (int ks = 0; ks < 4; ks++) {
            bf16x8 pb = *(bf16x8*)&pw[ks];
            #pragma unroll
            for (int ht = 0; ht < 2; ht++) {
                bf16x8 va = *(const bf16x8*)&Vs[ht * 32 + l31][ks * 16 + h32 * 8];
                oacc[ht] = __builtin_amdgcn_mfma_f32_32x32x16_bf16(va, pb, oacc[ht], 0, 0, 0);
            }
        }
        __builtin_amdgcn_s_setprio(0);

        if (kt < NT - 1) {
            __syncthreads();
            #pragma unroll
            for (int i = 0; i < 4; i++) {
                *(bf16x8*)&Ks[srow][scb + i * 8] = kpre[i];
                *(bf16x8*)&Vs[srow][scb + i * 8] = vpre[i];
            }
            __syncthreads();
        }
    }

    // ---- merge groups: pure sums (m=0 shared reference). LDS reused as f32.
    float l_run = xswap_add(l_part);
    __syncthreads();
    float* mg = (float*)&sm[0][0][0][0];
    constexpr int SLOT = 64 * 69;
    constexpr int LBASE = 3 * SLOT;
    const int qloc = wq * 32 + l31;
    if (gk > 0) {
        float* ob = mg + (gk - 1) * SLOT + qloc * 69;
        #pragma unroll
        for (int ht = 0; ht < 2; ht++)
            #pragma unroll
            for (int r = 0; r < 16; r++)
                ob[ht * 32 + (r & 3) + 8 * (r >> 2) + 4 * h32] = oacc[ht][r];
        if (h32 == 0) mg[LBASE + (gk - 1) * 64 + qloc] = l_run;
    }
    __syncthreads();
    if (gk == 0) {
        float l_tot = l_run + mg[LBASE + qloc] + mg[LBASE + 64 + qloc] + mg[LBASE + 128 + qloc];
        float linv = 1.0f / l_tot;
        float* op = out + ((size_t)(b * NS + qt * 64 + qloc)) * NH;
        const float* o1 = mg + qloc * 69;
        #pragma unroll
        for (int ht = 0; ht < 2; ht++)
            #pragma unroll
            for (int r = 0; r < 16; r++) {
                int hv = ht * 32 + (r & 3) + 8 * (r >> 2) + 4 * h32;
                float s = oacc[ht][r] + o1[hv] + o1[SLOT + hv] + o1[2 * SLOT + hv];
                op[hv] = s * linv;
            }
    }
}

// ---------------- launcher ---------------------------------------------------
extern "C" void kernel_launch(void* const* d_in, const int* in_sizes, int n_in,
                              void* d_out, int out_size, void* d_ws, size_t ws_size,
                              hipStream_t stream)
{
    const float* x  = (const float*)d_in[0];
    const float* Wq = (const float*)d_in[1];
    const float* bq = (const float*)d_in[2];
    const float* Wk = (const float*)d_in[3];
    const float* bk = (const float*)d_in[4];
    const float* Wv = (const float*)d_in[5];
    const float* bv = (const float*)d_in[6];
    float* out = (float*)d_out;

    const size_t qkv_elems = (size_t)NB * NS * NH;   // 2,097,152
    short* Qw  = (short*)d_ws;
    short* Kw  = Qw + qkv_elems;
    short* Vwt = Kw + qkv_elems;                     // [B][64][1024]
    short* Wtf = Vwt + qkv_elems;                    // 192*768 bf16, fragment-major

    wtrans_kernel<<<576, 256, 0, stream>>>(Wq, Wk, Wv, Wtf);
    qkv_kernel<<<(NB * NS) / 32, 512, 0, stream>>>(x, Wtf, bq, bk, bv, Qw, Kw, Vwt);
    attn_kernel<<<dim3(NS / 64, NB), 512, 0, stream>>>(Qw, Kw, Vwt, out);
}

// Round 11
// 62.534 us; speedup vs baseline: 1.4431x; 1.1800x over previous
//
#include <hip/hip_runtime.h>
#include <hip/hip_bf16.h>

// B=32, S=1024, D=768, HD=64 single-head attention, scores scaled 1/D.
// Inputs fp32, output fp32 [B,S,HD].
// Pipeline: (0) W -> bf16 fragment-major Wtf, (1) QKV proj: R4-proven
// 2-barrier K-step skeleton, A-only LDS (9.2 KB), depth-1 reg prefetch,
// B lane-linear from L2-resident fragment-major Wtf, 512 thr = 8 waves,
// 16 waves/CU. Q pre-scaled by 1/768*log2e, V stored transposed [B][H][S].
// (2) flash attention, 32x32 swapped-QK^T, max-free exp2 softmax,
// 4-way key-split + sum-merge.

constexpr int NB = 32;
constexpr int NS = 1024;
constexpr int ND = 768;
constexpr int NH = 64;
constexpr float SC2 = (1.0f / 768.0f) * 1.4426950408889634f;

typedef __attribute__((ext_vector_type(8))) short bf16x8;
typedef __attribute__((ext_vector_type(4))) float f32x4;
typedef __attribute__((ext_vector_type(16))) float f32x16;
typedef __attribute__((ext_vector_type(4))) unsigned int u32x4;

__device__ __forceinline__ unsigned short f2bf(float f) {
    unsigned int u = __float_as_uint(f);
    u += 0x7FFFu + ((u >> 16) & 1u);   // RNE
    return (unsigned short)(u >> 16);
}

__device__ __forceinline__ unsigned int pkbf(float lo, float hi) {
    __hip_bfloat162 h = __float22bfloat162_rn(float2{lo, hi});
    return *reinterpret_cast<unsigned int*>(&h);
}

__device__ __forceinline__ void pl32swap(unsigned int a, unsigned int b,
                                         unsigned int& x, unsigned int& y) {
    auto r = __builtin_amdgcn_permlane32_swap((int)a, (int)b, false, false);
    x = (unsigned int)r[0];
    y = (unsigned int)r[1];
}

__device__ __forceinline__ float xswap_add(float v) {
    unsigned int a, b;
    pl32swap(__float_as_uint(v), __float_as_uint(v), a, b);
    return __uint_as_float(a) + __uint_as_float(b);
}

// ---------------- Kernel 0: W -> fragment-major Wtf --------------------------
// Position p = f*512 + lane*8 + e holds W_n[k] with f = nt*24+ks,
// n = nt*16 + (lane&15), k = ks*32 + (lane>>4)*8 + e.
__global__ void wtrans_kernel(const float* __restrict__ Wq, const float* __restrict__ Wk,
                              const float* __restrict__ Wv, short* __restrict__ Wtf) {
    int idx = blockIdx.x * 256 + threadIdx.x;      // 147456 = 576*256
    int f = idx >> 9, q = idx & 511;
    int lane = q >> 3, e = q & 7;
    int ln = lane & 15, g = lane >> 4;
    int nt = f / 24, ks = f - nt * 24;
    int n = nt * 16 + ln;
    int k = ks * 32 + g * 8 + e;
    const float* W = (n < 64) ? Wq : ((n < 128) ? Wk : Wv);
    Wtf[idx] = (short)f2bf(W[(size_t)k * NH + (n & 63)]);
}

// ---------------- Kernel 1: QKV projection -----------------------------------
// Tile: 64 M x 192 N, K-step 64. 512 thr = 8 waves (wm in {0,1} x wn in 0..3);
// wave computes rows [wm*32,+32) x cols [wn*48,+48). A-only LDS staging with
// depth-1 prefetch; B lane-linear from fragment-major Wtf (L2-resident).
__global__ __launch_bounds__(512, 4) void qkv_kernel(
    const float* __restrict__ x, const short* __restrict__ Wtf,
    const float* __restrict__ bq, const float* __restrict__ bk, const float* __restrict__ bv,
    short* __restrict__ Qw, short* __restrict__ Kw, short* __restrict__ Vwt)
{
    __shared__ __align__(16) short As[64][72];     // 9.2 KB, +8 pad

    const int t = threadIdx.x;
    const int w = t >> 6, lane = t & 63, ln = lane & 15, g = lane >> 4;
    const int wm = w >> 2, wn = w & 3;
    const int m0 = blockIdx.x * 64;

    // staging cover: thread t -> row t>>3, 8-col chunk (t&7)*8
    const int srow = t >> 3, scol = (t & 7) * 8;
    const float* xr = x + (size_t)(m0 + srow) * ND + scol;

    const short* bbase = Wtf + (size_t)(wn * 3) * 24 * 512 + lane * 8;

    f32x4 acc[2][3];
    #pragma unroll
    for (int i = 0; i < 2; i++)
        #pragma unroll
        for (int j = 0; j < 3; j++) acc[i][j] = f32x4{0.f, 0.f, 0.f, 0.f};

    float4 xp0 = *(const float4*)(xr);
    float4 xp1 = *(const float4*)(xr + 4);

    #pragma unroll 1
    for (int kt = 0; kt < 12; kt++) {
        __syncthreads();   // previous compute done reading As
        {
            u32x4 v{pkbf(xp0.x, xp0.y), pkbf(xp0.z, xp0.w),
                    pkbf(xp1.x, xp1.y), pkbf(xp1.z, xp1.w)};
            *(u32x4*)&As[srow][scol] = v;
        }
        __syncthreads();

        if (kt < 11) {   // depth-1 prefetch of next A tile (HBM)
            xp0 = *(const float4*)(xr + (kt + 1) * 64);
            xp1 = *(const float4*)(xr + (kt + 1) * 64 + 4);
        }

        // B fragments (L2, lane-linear): ks pair for this K-step
        bf16x8 b0[3], b1[3];
        #pragma unroll
        for (int nf = 0; nf < 3; nf++) {
            b0[nf] = *(const bf16x8*)(bbase + (nf * 24 + kt * 2) * 512);
            b1[nf] = *(const bf16x8*)(bbase + (nf * 24 + kt * 2 + 1) * 512);
        }
        // A fragments from LDS
        bf16x8 af0[2], af1[2];
        #pragma unroll
        for (int mf = 0; mf < 2; mf++) {
            af0[mf] = *(const bf16x8*)&As[wm * 32 + mf * 16 + ln][g * 8];
            af1[mf] = *(const bf16x8*)&As[wm * 32 + mf * 16 + ln][32 + g * 8];
        }
        __builtin_amdgcn_s_setprio(1);
        #pragma unroll
        for (int mf = 0; mf < 2; mf++)
            #pragma unroll
            for (int nf = 0; nf < 3; nf++) {
                acc[mf][nf] = __builtin_amdgcn_mfma_f32_16x16x32_bf16(
                    af0[mf], b0[nf], acc[mf][nf], 0, 0, 0);
                acc[mf][nf] = __builtin_amdgcn_mfma_f32_16x16x32_bf16(
                    af1[mf], b1[nf], acc[mf][nf], 0, 0, 0);
            }
        __builtin_amdgcn_s_setprio(0);
    }

    // ---- epilogue: +bias (Q also * SC2), cast bf16, store
    #pragma unroll
    for (int nf = 0; nf < 3; nf++) {
        int n = wn * 48 + nf * 16 + ln;
        int mat = n >> 6, col = n & 63;
        const float* bp = (mat == 0) ? bq : ((mat == 1) ? bk : bv);
        float bias = bp[col];
        #pragma unroll
        for (int mf = 0; mf < 2; mf++) {
            int rbase = m0 + wm * 32 + mf * 16 + g * 4;
            #pragma unroll
            for (int r = 0; r < 4; r++) {
                float v = acc[mf][nf][r] + bias;
                int row = rbase + r;
                if (mat == 0) {
                    Qw[(size_t)row * NH + col] = (short)f2bf(v * SC2);
                } else if (mat == 1) {
                    Kw[(size_t)row * NH + col] = (short)f2bf(v);
                } else {
                    int bb = row >> 10, ss = row & 1023;
                    Vwt[((size_t)bb * NH + col) * NS + ss] = (short)f2bf(v);
                }
            }
        }
    }
}

// ---------------- Kernel 2: flash attention (32x32 swapped QK^T) -------------
// Grid: (16 q-tiles, 32 batches), 512 threads = 8 waves = 4 key-groups x 2 q-waves.
__global__ __launch_bounds__(512, 4) void attn_kernel(
    const short* __restrict__ Qw, const short* __restrict__ Kw,
    const short* __restrict__ Vwt, float* __restrict__ out)
{
    __shared__ __align__(16) short sm[4][2][64][72];  // [gk][0]=K, [gk][1]=V

    const int t = threadIdx.x;
    const int w = t >> 6;
    const int lane = t & 63, l31 = lane & 31, h32 = lane >> 5;
    const int gk = w >> 1, wq = w & 1;
    const int b = blockIdx.y, qt = blockIdx.x;

    short (*Ks)[72] = sm[gk][0];
    short (*Vs)[72] = sm[gk][1];

    const short* qbase = Qw + ((size_t)(b * NS + qt * 64 + wq * 32 + l31)) * NH + h32 * 8;
    bf16x8 qf[4];
    #pragma unroll
    for (int ks = 0; ks < 4; ks++) qf[ks] = *(const bf16x8*)(qbase + ks * 16);

    f32x16 oacc[2];
    #pragma unroll
    for (int i = 0; i < 16; i++) { oacc[0][i] = 0.f; oacc[1][i] = 0.f; }
    float l_part = 0.f;

    const int tg = t & 127;
    const int srow = tg >> 1, scb = (tg & 1) * 32;
    const int key00 = gk * 256;
    const short* ksrc = Kw + ((size_t)(b * NS + key00 + srow)) * NH + scb;
    const short* vsrc = Vwt + ((size_t)(b * NH + srow)) * NS + key00 + scb;

    bf16x8 kpre[4], vpre[4];
    #pragma unroll
    for (int i = 0; i < 4; i++) {
        kpre[i] = *(const bf16x8*)(ksrc + i * 8);
        vpre[i] = *(const bf16x8*)(vsrc + i * 8);
    }
    #pragma unroll
    for (int i = 0; i < 4; i++) {
        *(bf16x8*)&Ks[srow][scb + i * 8] = kpre[i];
        *(bf16x8*)&Vs[srow][scb + i * 8] = vpre[i];
    }
    __syncthreads();

    constexpr int NT = 4;
    for (int kt = 0; kt < NT; kt++) {
        if (kt < NT - 1) {
            const short* kp = ksrc + (size_t)(kt + 1) * 64 * NH;
            const short* vp = vsrc + (kt + 1) * 64;
            #pragma unroll
            for (int i = 0; i < 4; i++) {
                kpre[i] = *(const bf16x8*)(kp + i * 8);
                vpre[i] = *(const bf16x8*)(vp + i * 8);
            }
        }

        float sl = 0.f;
        u32x4 pw[4];

        // ---- keys [0,32): S^T = K*Q^T, exp2, pack -> pw[0..1]
        {
            f32x16 st;
            #pragma unroll
            for (int i = 0; i < 16; i++) st[i] = 0.f;
            __builtin_amdgcn_s_setprio(1);
            #pragma unroll
            for (int ks = 0; ks < 4; ks++) {
                bf16x8 a0 = *(const bf16x8*)&Ks[l31][ks * 16 + h32 * 8];
                st = __builtin_amdgcn_mfma_f32_32x32x16_bf16(a0, qf[ks], st, 0, 0, 0);
            }
            __builtin_amdgcn_s_setprio(0);
            #pragma unroll
            for (int i = 0; i < 16; i++) { st[i] = exp2f(st[i]); sl += st[i]; }
            unsigned int c[8];
            #pragma unroll
            for (int i = 0; i < 8; i++) c[i] = pkbf(st[2 * i], st[2 * i + 1]);
            unsigned int w0, w1, w2, w3;
            pl32swap(c[0], c[2], w0, w2); pl32swap(c[1], c[3], w1, w3);
            pw[0] = u32x4{w0, w1, w2, w3};
            pl32swap(c[4], c[6], w0, w2); pl32swap(c[5], c[7], w1, w3);
            pw[1] = u32x4{w0, w1, w2, w3};
        }
        // ---- keys [32,64)
        {
            f32x16 st;
            #pragma unroll
            for (int i = 0; i < 16; i++) st[i] = 0.f;
            __builtin_amdgcn_s_setprio(1);
            #pragma unroll
            for (int ks = 0; ks < 4; ks++) {
                bf16x8 a1 = *(const bf16x8*)&Ks[32 + l31][ks * 16 + h32 * 8];
                st = __builtin_amdgcn_mfma_f32_32x32x16_bf16(a1, qf[ks], st, 0, 0, 0);
            }
            __builtin_amdgcn_s_setprio(0);
            #pragma unroll
            for (int i = 0; i < 16; i++) { st[i] = exp2f(st[i]); sl += st[i]; }
            unsigned int c[8];
            #pragma unroll
            for (int i = 0; i < 8; i++) c[i] = pkbf(st[2 * i], st[2 * i + 1]);
            unsigned int w0, w1, w2, w3;
            pl32swap(c[0], c[2], w0, w2); pl32swap(c[1], c[3], w1, w3);
            pw[2] = u32x4{w0, w1, w2, w3};
            pl32swap(c[4], c[6], w0, w2); pl32swap(c[5], c[7], w1, w3);
            pw[3] = u32x4{w0, w1, w2, w3};
        }
        l_part += sl;

        // ---- O^T += V^T * P^T
        __builtin_amdgcn_s_setprio(1);
        #pragma unroll
        for (int ks = 0; ks < 4; ks++) {
            bf16x8 pb = *(bf16x8*)&pw[ks];
            #pragma unroll
            for (int ht = 0; ht < 2; ht++) {
                bf16x8 va = *(const bf16x8*)&Vs[ht * 32 + l31][ks * 16 + h32 * 8];
                oacc[ht] = __builtin_amdgcn_mfma_f32_32x32x16_bf16(va, pb, oacc[ht], 0, 0, 0);
            }
        }
        __builtin_amdgcn_s_setprio(0);

        if (kt < NT - 1) {
            __syncthreads();
            #pragma unroll
            for (int i = 0; i < 4; i++) {
                *(bf16x8*)&Ks[srow][scb + i * 8] = kpre[i];
                *(bf16x8*)&Vs[srow][scb + i * 8] = vpre[i];
            }
            __syncthreads();
        }
    }

    // ---- merge groups: pure sums (m=0 shared reference). LDS reused as f32.
    float l_run = xswap_add(l_part);
    __syncthreads();
    float* mg = (float*)&sm[0][0][0][0];
    constexpr int SLOT = 64 * 69;
    constexpr int LBASE = 3 * SLOT;
    const int qloc = wq * 32 + l31;
    if (gk > 0) {
        float* ob = mg + (gk - 1) * SLOT + qloc * 69;
        #pragma unroll
        for (int ht = 0; ht < 2; ht++)
            #pragma unroll
            for (int r = 0; r < 16; r++)
                ob[ht * 32 + (r & 3) + 8 * (r >> 2) + 4 * h32] = oacc[ht][r];
        if (h32 == 0) mg[LBASE + (gk - 1) * 64 + qloc] = l_run;
    }
    __syncthreads();
    if (gk == 0) {
        float l_tot = l_run + mg[LBASE + qloc] + mg[LBASE + 64 + qloc] + mg[LBASE + 128 + qloc];
        float linv = 1.0f / l_tot;
        float* op = out + ((size_t)(b * NS + qt * 64 + qloc)) * NH;
        const float* o1 = mg + qloc * 69;
        #pragma unroll
        for (int ht = 0; ht < 2; ht++)
            #pragma unroll
            for (int r = 0; r < 16; r++) {
                int hv = ht * 32 + (r & 3) + 8 * (r >> 2) + 4 * h32;
                float s = oacc[ht][r] + o1[hv] + o1[SLOT + hv] + o1[2 * SLOT + hv];
                op[hv] = s * linv;
            }
    }
}

// ---------------- launcher ---------------------------------------------------
extern "C" void kernel_launch(void* const* d_in, const int* in_sizes, int n_in,
                              void* d_out, int out_size, void* d_ws, size_t ws_size,
                              hipStream_t stream)
{
    const float* x  = (const float*)d_in[0];
    const float* Wq = (const float*)d_in[1];
    const float* bq = (const float*)d_in[2];
    const float* Wk = (const float*)d_in[3];
    const float* bk = (const float*)d_in[4];
    const float* Wv = (const float*)d_in[5];
    const float* bv = (const float*)d_in[6];
    float* out = (float*)d_out;

    const size_t qkv_elems = (size_t)NB * NS * NH;   // 2,097,152
    short* Qw  = (short*)d_ws;
    short* Kw  = Qw + qkv_elems;
    short* Vwt = Kw + qkv_elems;                     // [B][64][1024]
    short* Wtf = Vwt + qkv_elems;                    // 192*768 bf16, fragment-major

    wtrans_kernel<<<576, 256, 0, stream>>>(Wq, Wk, Wv, Wtf);
    qkv_kernel<<<(NB * NS) / 64, 512, 0, stream>>>(x, Wtf, bq, bk, bv, Qw, Kw, Vwt);
    attn_kernel<<<dim3(NS / 64, NB), 512, 0, stream>>>(Qw, Kw, Vwt, out);
}

// Round 12
// 59.070 us; speedup vs baseline: 1.5277x; 1.0586x over previous
//
#include <hip/hip_runtime.h>
#include <hip/hip_bf16.h>

// B=32, S=1024, D=768, HD=64 single-head attention, scores scaled 1/D.
// Inputs fp32, output fp32 [B,S,HD].
// Pipeline: (0) W -> bf16 fragment-major Wtf, (1) QKV proj: 2-barrier K-step,
// A-only LDS (9.2 KB) with depth-1 reg prefetch; B fragments lane-linear from
// L2-resident Wtf, ISSUED AT TOP OF LOOP (before both barriers) so their L2
// latency hides under barrier+stage+ds_read. 512 thr = 8 waves, 16 waves/CU.
// Q pre-scaled by 1/768*log2e, V stored transposed [B][H][S].
// (2) flash attention, 32x32 swapped-QK^T, max-free exp2 softmax,
// 4-way key-split + sum-merge.

constexpr int NB = 32;
constexpr int NS = 1024;
constexpr int ND = 768;
constexpr int NH = 64;
constexpr float SC2 = (1.0f / 768.0f) * 1.4426950408889634f;

typedef __attribute__((ext_vector_type(8))) short bf16x8;
typedef __attribute__((ext_vector_type(4))) float f32x4;
typedef __attribute__((ext_vector_type(16))) float f32x16;
typedef __attribute__((ext_vector_type(4))) unsigned int u32x4;

__device__ __forceinline__ unsigned short f2bf(float f) {
    unsigned int u = __float_as_uint(f);
    u += 0x7FFFu + ((u >> 16) & 1u);   // RNE
    return (unsigned short)(u >> 16);
}

__device__ __forceinline__ unsigned int pkbf(float lo, float hi) {
    __hip_bfloat162 h = __float22bfloat162_rn(float2{lo, hi});
    return *reinterpret_cast<unsigned int*>(&h);
}

__device__ __forceinline__ void pl32swap(unsigned int a, unsigned int b,
                                         unsigned int& x, unsigned int& y) {
    auto r = __builtin_amdgcn_permlane32_swap((int)a, (int)b, false, false);
    x = (unsigned int)r[0];
    y = (unsigned int)r[1];
}

__device__ __forceinline__ float xswap_add(float v) {
    unsigned int a, b;
    pl32swap(__float_as_uint(v), __float_as_uint(v), a, b);
    return __uint_as_float(a) + __uint_as_float(b);
}

// ---------------- Kernel 0: W -> fragment-major Wtf --------------------------
// Position p = f*512 + lane*8 + e holds W_n[k] with f = nt*24+ks,
// n = nt*16 + (lane&15), k = ks*32 + (lane>>4)*8 + e.
__global__ void wtrans_kernel(const float* __restrict__ Wq, const float* __restrict__ Wk,
                              const float* __restrict__ Wv, short* __restrict__ Wtf) {
    int idx = blockIdx.x * 256 + threadIdx.x;      // 147456 = 576*256
    int f = idx >> 9, q = idx & 511;
    int lane = q >> 3, e = q & 7;
    int ln = lane & 15, g = lane >> 4;
    int nt = f / 24, ks = f - nt * 24;
    int n = nt * 16 + ln;
    int k = ks * 32 + g * 8 + e;
    const float* W = (n < 64) ? Wq : ((n < 128) ? Wk : Wv);
    Wtf[idx] = (short)f2bf(W[(size_t)k * NH + (n & 63)]);
}

// ---------------- Kernel 1: QKV projection -----------------------------------
// Tile: 64 M x 192 N, K-step 64. 512 thr = 8 waves (wm in {0,1} x wn in 0..3);
// wave computes rows [wm*32,+32) x cols [wn*48,+48).
__global__ __launch_bounds__(512, 4) void qkv_kernel(
    const float* __restrict__ x, const short* __restrict__ Wtf,
    const float* __restrict__ bq, const float* __restrict__ bk, const float* __restrict__ bv,
    short* __restrict__ Qw, short* __restrict__ Kw, short* __restrict__ Vwt)
{
    __shared__ __align__(16) short As[64][72];     // 9.2 KB, +8 pad

    const int t = threadIdx.x;
    const int w = t >> 6, lane = t & 63, ln = lane & 15, g = lane >> 4;
    const int wm = w >> 2, wn = w & 3;
    const int m0 = blockIdx.x * 64;

    // staging cover: thread t -> row t>>3, 8-col chunk (t&7)*8
    const int srow = t >> 3, scol = (t & 7) * 8;
    const float* xr = x + (size_t)(m0 + srow) * ND + scol;

    const short* bbase = Wtf + (size_t)(wn * 3) * 24 * 512 + lane * 8;

    f32x4 acc[2][3];
    #pragma unroll
    for (int i = 0; i < 2; i++)
        #pragma unroll
        for (int j = 0; j < 3; j++) acc[i][j] = f32x4{0.f, 0.f, 0.f, 0.f};

    float4 xp0 = *(const float4*)(xr);
    float4 xp1 = *(const float4*)(xr + 4);

    #pragma unroll 1
    for (int kt = 0; kt < 12; kt++) {
        // B fragments for THIS step: issue before both barriers — their L2
        // latency hides under barrier + LDS write + barrier + ds_reads.
        bf16x8 b0[3], b1[3];
        #pragma unroll
        for (int nf = 0; nf < 3; nf++) {
            b0[nf] = *(const bf16x8*)(bbase + (nf * 24 + kt * 2) * 512);
            b1[nf] = *(const bf16x8*)(bbase + (nf * 24 + kt * 2 + 1) * 512);
        }

        __syncthreads();   // previous compute done reading As
        {
            u32x4 v{pkbf(xp0.x, xp0.y), pkbf(xp0.z, xp0.w),
                    pkbf(xp1.x, xp1.y), pkbf(xp1.z, xp1.w)};
            *(u32x4*)&As[srow][scol] = v;
        }
        __syncthreads();

        if (kt < 11) {   // depth-1 prefetch of next A tile (HBM)
            xp0 = *(const float4*)(xr + (kt + 1) * 64);
            xp1 = *(const float4*)(xr + (kt + 1) * 64 + 4);
        }

        // A fragments from LDS
        bf16x8 af0[2], af1[2];
        #pragma unroll
        for (int mf = 0; mf < 2; mf++) {
            af0[mf] = *(const bf16x8*)&As[wm * 32 + mf * 16 + ln][g * 8];
            af1[mf] = *(const bf16x8*)&As[wm * 32 + mf * 16 + ln][32 + g * 8];
        }
        __builtin_amdgcn_s_setprio(1);
        #pragma unroll
        for (int mf = 0; mf < 2; mf++)
            #pragma unroll
            for (int nf = 0; nf < 3; nf++) {
                acc[mf][nf] = __builtin_amdgcn_mfma_f32_16x16x32_bf16(
                    af0[mf], b0[nf], acc[mf][nf], 0, 0, 0);
                acc[mf][nf] = __builtin_amdgcn_mfma_f32_16x16x32_bf16(
                    af1[mf], b1[nf], acc[mf][nf], 0, 0, 0);
            }
        __builtin_amdgcn_s_setprio(0);
    }

    // ---- epilogue: +bias (Q also * SC2), cast bf16, store
    #pragma unroll
    for (int nf = 0; nf < 3; nf++) {
        int n = wn * 48 + nf * 16 + ln;
        int mat = n >> 6, col = n & 63;
        const float* bp = (mat == 0) ? bq : ((mat == 1) ? bk : bv);
        float bias = bp[col];
        #pragma unroll
        for (int mf = 0; mf < 2; mf++) {
            int rbase = m0 + wm * 32 + mf * 16 + g * 4;
            #pragma unroll
            for (int r = 0; r < 4; r++) {
                float v = acc[mf][nf][r] + bias;
                int row = rbase + r;
                if (mat == 0) {
                    Qw[(size_t)row * NH + col] = (short)f2bf(v * SC2);
                } else if (mat == 1) {
                    Kw[(size_t)row * NH + col] = (short)f2bf(v);
                } else {
                    int bb = row >> 10, ss = row & 1023;
                    Vwt[((size_t)bb * NH + col) * NS + ss] = (short)f2bf(v);
                }
            }
        }
    }
}

// ---------------- Kernel 2: flash attention (32x32 swapped QK^T) -------------
// Grid: (16 q-tiles, 32 batches), 512 threads = 8 waves = 4 key-groups x 2 q-waves.
__global__ __launch_bounds__(512, 4) void attn_kernel(
    const short* __restrict__ Qw, const short* __restrict__ Kw,
    const short* __restrict__ Vwt, float* __restrict__ out)
{
    __shared__ __align__(16) short sm[4][2][64][72];  // [gk][0]=K, [gk][1]=V

    const int t = threadIdx.x;
    const int w = t >> 6;
    const int lane = t & 63, l31 = lane & 31, h32 = lane >> 5;
    const int gk = w >> 1, wq = w & 1;
    const int b = blockIdx.y, qt = blockIdx.x;

    short (*Ks)[72] = sm[gk][0];
    short (*Vs)[72] = sm[gk][1];

    const short* qbase = Qw + ((size_t)(b * NS + qt * 64 + wq * 32 + l31)) * NH + h32 * 8;
    bf16x8 qf[4];
    #pragma unroll
    for (int ks = 0; ks < 4; ks++) qf[ks] = *(const bf16x8*)(qbase + ks * 16);

    f32x16 oacc[2];
    #pragma unroll
    for (int i = 0; i < 16; i++) { oacc[0][i] = 0.f; oacc[1][i] = 0.f; }
    float l_part = 0.f;

    const int tg = t & 127;
    const int srow = tg >> 1, scb = (tg & 1) * 32;
    const int key00 = gk * 256;
    const short* ksrc = Kw + ((size_t)(b * NS + key00 + srow)) * NH + scb;
    const short* vsrc = Vwt + ((size_t)(b * NH + srow)) * NS + key00 + scb;

    bf16x8 kpre[4], vpre[4];
    #pragma unroll
    for (int i = 0; i < 4; i++) {
        kpre[i] = *(const bf16x8*)(ksrc + i * 8);
        vpre[i] = *(const bf16x8*)(vsrc + i * 8);
    }
    #pragma unroll
    for (int i = 0; i < 4; i++) {
        *(bf16x8*)&Ks[srow][scb + i * 8] = kpre[i];
        *(bf16x8*)&Vs[srow][scb + i * 8] = vpre[i];
    }
    __syncthreads();

    constexpr int NT = 4;
    for (int kt = 0; kt < NT; kt++) {
        if (kt < NT - 1) {
            const short* kp = ksrc + (size_t)(kt + 1) * 64 * NH;
            const short* vp = vsrc + (kt + 1) * 64;
            #pragma unroll
            for (int i = 0; i < 4; i++) {
                kpre[i] = *(const bf16x8*)(kp + i * 8);
                vpre[i] = *(const bf16x8*)(vp + i * 8);
            }
        }

        float sl = 0.f;
        u32x4 pw[4];

        // ---- keys [0,32): S^T = K*Q^T, exp2, pack -> pw[0..1]
        {
            f32x16 st;
            #pragma unroll
            for (int i = 0; i < 16; i++) st[i] = 0.f;
            __builtin_amdgcn_s_setprio(1);
            #pragma unroll
            for (int ks = 0; ks < 4; ks++) {
                bf16x8 a0 = *(const bf16x8*)&Ks[l31][ks * 16 + h32 * 8];
                st = __builtin_amdgcn_mfma_f32_32x32x16_bf16(a0, qf[ks], st, 0, 0, 0);
            }
            __builtin_amdgcn_s_setprio(0);
            #pragma unroll
            for (int i = 0; i < 16; i++) { st[i] = exp2f(st[i]); sl += st[i]; }
            unsigned int c[8];
            #pragma unroll
            for (int i = 0; i < 8; i++) c[i] = pkbf(st[2 * i], st[2 * i + 1]);
            unsigned int w0, w1, w2, w3;
            pl32swap(c[0], c[2], w0, w2); pl32swap(c[1], c[3], w1, w3);
            pw[0] = u32x4{w0, w1, w2, w3};
            pl32swap(c[4], c[6], w0, w2); pl32swap(c[5], c[7], w1, w3);
            pw[1] = u32x4{w0, w1, w2, w3};
        }
        // ---- keys [32,64)
        {
            f32x16 st;
            #pragma unroll
            for (int i = 0; i < 16; i++) st[i] = 0.f;
            __builtin_amdgcn_s_setprio(1);
            #pragma unroll
            for (int ks = 0; ks < 4; ks++) {
                bf16x8 a1 = *(const bf16x8*)&Ks[32 + l31][ks * 16 + h32 * 8];
                st = __builtin_amdgcn_mfma_f32_32x32x16_bf16(a1, qf[ks], st, 0, 0, 0);
            }
            __builtin_amdgcn_s_setprio(0);
            #pragma unroll
            for (int i = 0; i < 16; i++) { st[i] = exp2f(st[i]); sl += st[i]; }
            unsigned int c[8];
            #pragma unroll
            for (int i = 0; i < 8; i++) c[i] = pkbf(st[2 * i], st[2 * i + 1]);
            unsigned int w0, w1, w2, w3;
            pl32swap(c[0], c[2], w0, w2); pl32swap(c[1], c[3], w1, w3);
            pw[2] = u32x4{w0, w1, w2, w3};
            pl32swap(c[4], c[6], w0, w2); pl32swap(c[5], c[7], w1, w3);
            pw[3] = u32x4{w0, w1, w2, w3};
        }
        l_part += sl;

        // ---- O^T += V^T * P^T
        __builtin_amdgcn_s_setprio(1);
        #pragma unroll
        for (int ks = 0; ks < 4; ks++) {
            bf16x8 pb = *(bf16x8*)&pw[ks];
            #pragma unroll
            for (int ht = 0; ht < 2; ht++) {
                bf16x8 va = *(const bf16x8*)&Vs[ht * 32 + l31][ks * 16 + h32 * 8];
                oacc[ht] = __builtin_amdgcn_mfma_f32_32x32x16_bf16(va, pb, oacc[ht], 0, 0, 0);
            }
        }
        __builtin_amdgcn_s_setprio(0);

        if (kt < NT - 1) {
            __syncthreads();
            #pragma unroll
            for (int i = 0; i < 4; i++) {
                *(bf16x8*)&Ks[srow][scb + i * 8] = kpre[i];
                *(bf16x8*)&Vs[srow][scb + i * 8] = vpre[i];
            }
            __syncthreads();
        }
    }

    // ---- merge groups: pure sums (m=0 shared reference). LDS reused as f32.
    float l_run = xswap_add(l_part);
    __syncthreads();
    float* mg = (float*)&sm[0][0][0][0];
    constexpr int SLOT = 64 * 69;
    constexpr int LBASE = 3 * SLOT;
    const int qloc = wq * 32 + l31;
    if (gk > 0) {
        float* ob = mg + (gk - 1) * SLOT + qloc * 69;
        #pragma unroll
        for (int ht = 0; ht < 2; ht++)
            #pragma unroll
            for (int r = 0; r < 16; r++)
                ob[ht * 32 + (r & 3) + 8 * (r >> 2) + 4 * h32] = oacc[ht][r];
        if (h32 == 0) mg[LBASE + (gk - 1) * 64 + qloc] = l_run;
    }
    __syncthreads();
    if (gk == 0) {
        float l_tot = l_run + mg[LBASE + qloc] + mg[LBASE + 64 + qloc] + mg[LBASE + 128 + qloc];
        float linv = 1.0f / l_tot;
        float* op = out + ((size_t)(b * NS + qt * 64 + qloc)) * NH;
        const float* o1 = mg + qloc * 69;
        #pragma unroll
        for (int ht = 0; ht < 2; ht++)
            #pragma unroll
            for (int r = 0; r < 16; r++) {
                int hv = ht * 32 + (r & 3) + 8 * (r >> 2) + 4 * h32;
                float s = oacc[ht][r] + o1[hv] + o1[SLOT + hv] + o1[2 * SLOT + hv];
                op[hv] = s * linv;
            }
    }
}

// ---------------- launcher ---------------------------------------------------
extern "C" void kernel_launch(void* const* d_in, const int* in_sizes, int n_in,
                              void* d_out, int out_size, void* d_ws, size_t ws_size,
                              hipStream_t stream)
{
    const float* x  = (const float*)d_in[0];
    const float* Wq = (const float*)d_in[1];
    const float* bq = (const float*)d_in[2];
    const float* Wk = (const float*)d_in[3];
    const float* bk = (const float*)d_in[4];
    const float* Wv = (const float*)d_in[5];
    const float* bv = (const float*)d_in[6];
    float* out = (float*)d_out;

    const size_t qkv_elems = (size_t)NB * NS * NH;   // 2,097,152
    short* Qw  = (short*)d_ws;
    short* Kw  = Qw + qkv_elems;
    short* Vwt = Kw + qkv_elems;                     // [B][64][1024]
    short* Wtf = Vwt + qkv_elems;                    // 192*768 bf16, fragment-major

    wtrans_kernel<<<576, 256, 0, stream>>>(Wq, Wk, Wv, Wtf);
    qkv_kernel<<<(NB * NS) / 64, 512, 0, stream>>>(x, Wtf, bq, bk, bv, Qw, Kw, Vwt);
    attn_kernel<<<dim3(NS / 64, NB), 512, 0, stream>>>(Qw, Kw, Vwt, out);
}